// Round 9
// baseline (148.682 us; speedup 1.0000x reference)
//
#include <hip/hip_runtime.h>
#include <hip/hip_bf16.h>
#include <stdint.h>

#define AS1 __attribute__((address_space(1)))
#define AS3 __attribute__((address_space(3)))

typedef short s16x8 __attribute__((ext_vector_type(8)));
typedef float f32x4 __attribute__((ext_vector_type(4)));
typedef unsigned int u32;

static constexpr int DDIM = 256;
static constexpr int NBLK = 1040;   // 2080 upper-triangle tiles / 2 per block
static constexpr float TEN_LOG2E = 14.4269504088896340736f; // 10 * log2(e)

// ---------------- Kernel 1: normalize + pack into MFMA-fragment order ----------------
// 512 blocks x 256 threads; block g handles rows [16g, 16g+16). packed layout:
// packed[((g*8 + kt)*64 + lane)*8 .. +8] = bf16 P[16g + (lane&15)][kt*32 + (lane>>4)*8 ..]
// Also zero-inits row_s[8192], done, and out[0].
__global__ __launch_bounds__(256) void normalize_pack_kernel(
    const float* __restrict__ zi, const float* __restrict__ zj,
    ushort* __restrict__ packed, float* __restrict__ row_s,
    int* __restrict__ done, float* __restrict__ out)
{
    __shared__ ushort lds[16 * 256];

    if (blockIdx.x < 8) {
        ((float4*)row_s)[blockIdx.x * 256 + threadIdx.x] = (float4){0.f, 0.f, 0.f, 0.f};
        if (blockIdx.x == 0 && threadIdx.x == 0) { out[0] = 0.0f; *done = 0; }
    }

    const int t = threadIdx.x;
    const int r = t >> 4;            // 0..15: row within group
    const int c = t & 15;            // 16 threads per row
    const int row = blockIdx.x * 16 + r;
    const float* src = (row < 4096) ? (zi + (size_t)row * DDIM)
                                    : (zj + (size_t)(row - 4096) * DDIM);
    float4 v[4];
    #pragma unroll
    for (int j = 0; j < 4; ++j) v[j] = ((const float4*)src)[c + j * 16];

    float ss = 0.0f;
    #pragma unroll
    for (int j = 0; j < 4; ++j)
        ss += v[j].x * v[j].x + v[j].y * v[j].y + v[j].z * v[j].z + v[j].w * v[j].w;
    ss += __shfl_xor(ss, 1, 64);
    ss += __shfl_xor(ss, 2, 64);
    ss += __shfl_xor(ss, 4, 64);
    ss += __shfl_xor(ss, 8, 64);
    const float inv = 1.0f / fmaxf(sqrtf(ss), 1e-8f);

    #pragma unroll
    for (int j = 0; j < 4; ++j) {
        ushort4 o;
        o.x = __builtin_bit_cast(unsigned short, __float2bfloat16(v[j].x * inv));
        o.y = __builtin_bit_cast(unsigned short, __float2bfloat16(v[j].y * inv));
        o.z = __builtin_bit_cast(unsigned short, __float2bfloat16(v[j].z * inv));
        o.w = __builtin_bit_cast(unsigned short, __float2bfloat16(v[j].w * inv));
        *(ushort4*)(lds + r * 256 + (c + j * 16) * 4) = o;
    }
    __syncthreads();

    #pragma unroll
    for (int h = 0; h < 2; ++h) {
        const int idx  = h * 256 + t;
        const int kt   = idx >> 6;
        const int lane = idx & 63;
        const int q    = lane >> 4;
        const int l15  = lane & 15;
        s16x8 frag = *(const s16x8*)(lds + l15 * 256 + kt * 32 + q * 8);
        ((s16x8*)packed)[(size_t)(blockIdx.x * 8 + kt) * 64 + lane] = frag;
    }
}

// ---------------- Kernel 2: paired-tile persistent blocks + fused finalize -----------
// 1040 blocks x 256 threads; block handles 2 consecutive upper-triangle 128x128 tiles
// (usually same row-strip -> A reuse). Per kt (K=32): A frags direct from packed
// (coalesced 1KB, issued before prefetch so their waitcnt leaves prefetch in flight),
// B panel kt staged in a 2-deep LDS buffer via global_load_lds(16B), 16 MFMA, one
// barrier. XCD-contiguous tile assignment for L2 locality. Positive-pair (tj==ti+32)
// diagonal extracted from acc. Last block (done-counter) sums log(row_s) -> out.
__global__ __launch_bounds__(256) void simexp_kernel(
    const ushort* __restrict__ packed,
    float* __restrict__ row_s,
    int* __restrict__ done,
    float* __restrict__ out)
{
    __shared__ __align__(16) ushort ldsB[2][4096];   // 2 x 8KB B-panel kt buffers

    const int tid  = threadIdx.x;
    const int w    = tid >> 6;
    const int lane = tid & 63;
    const int q    = lane >> 4;
    const int l15  = lane & 15;
    const int wm   = (w >> 1) * 64;  // wave row offset in tile
    const int wn   = (w & 1) * 64;   // wave col offset
    const int wgA  = (w >> 1) * 4;   // wave's first A group (of 8)
    const int wgB  = (w & 1) * 4;    // wave's first B group

    // XCD-contiguous virtual block id: blocks with equal (blockIdx%8) share an XCD and
    // get a contiguous tile range -> panel reuse within that XCD's L2.
    const int vb = (blockIdx.x & 7) * 130 + (blockIdx.x >> 3);
    const int T0 = vb * 2;

    // decode tile T0 -> (ti0, tj0); tile T0+1 follows in triangle order
    int ti0 = (int)(64.5f - sqrtf(64.5f * 64.5f - 2.0f * (float)T0));
    while ((ti0 + 1) * 64 - ((ti0 + 1) * ti0) / 2 <= T0) ++ti0;
    while (ti0 * 64 - (ti0 * (ti0 - 1)) / 2 > T0) --ti0;
    const int tj0 = ti0 + (T0 - (ti0 * 64 - (ti0 * (ti0 - 1)) / 2));
    int ti1, tj1;
    if (tj0 + 1 > 63) { ti1 = ti0 + 1; tj1 = ti1; }
    else              { ti1 = ti0;     tj1 = tj0 + 1; }
    const int tiA[2] = {ti0, ti1};
    const int tjA[2] = {tj0, tj1};

    // prologue: stage B(tile0, kt0) into buf 0
    #pragma unroll
    for (int kk = 0; kk < 2; ++kk) {
        const ushort* gb = packed + ((size_t)((tj0 * 8 + w * 2 + kk) * 8 + 0)) * 512
                         + (size_t)lane * 8;
        __builtin_amdgcn_global_load_lds((const AS1 u32*)gb,
                                         (AS3 u32*)(&ldsB[0][(w * 2 + kk) * 512]), 16, 0, 0);
    }
    __syncthreads();

    float blk_pos = 0.0f;
    bool  hadP    = false;

    #pragma unroll
    for (int tile = 0; tile < 2; ++tile) {
        const int ti = tiA[tile], tj = tjA[tile];
        const bool diag  = (ti == tj);
        const bool ptile = (tj == ti + 32);
        hadP = hadP || ptile;

        f32x4 acc[4][4];
        #pragma unroll
        for (int mi = 0; mi < 4; ++mi)
            #pragma unroll
            for (int ni = 0; ni < 4; ++ni)
                acc[mi][ni] = (f32x4){0.f, 0.f, 0.f, 0.f};

        #pragma unroll
        for (int kt = 0; kt < 8; ++kt) {
            const int it = tile * 8 + kt;

            // A fragments: direct coalesced loads (issued first -> oldest in vmcnt
            // queue; waiting on them leaves the B-prefetch below in flight)
            s16x8 af[4];
            #pragma unroll
            for (int mi = 0; mi < 4; ++mi)
                af[mi] = *(const s16x8*)(packed +
                    ((size_t)((ti * 8 + wgA + mi) * 8 + kt)) * 512 + (size_t)lane * 8);

            // prefetch next iteration's B-panel kt into the other buffer
            if (it < 15) {
                const int nt    = it + 1;
                const int ntile = nt >> 3;
                const int nkt   = nt & 7;
                const int ntj   = tjA[ntile];
                #pragma unroll
                for (int kk = 0; kk < 2; ++kk) {
                    const ushort* gb = packed +
                        ((size_t)((ntj * 8 + w * 2 + kk) * 8 + nkt)) * 512 + (size_t)lane * 8;
                    __builtin_amdgcn_global_load_lds((const AS1 u32*)gb,
                        (AS3 u32*)(&ldsB[nt & 1][(w * 2 + kk) * 512]), 16, 0, 0);
                }
            }

            // B fragments from LDS (identity layout, conflict-free)
            s16x8 bfr[4];
            #pragma unroll
            for (int ni = 0; ni < 4; ++ni)
                bfr[ni] = *(const s16x8*)(&ldsB[it & 1][(wgB + ni) * 512 + lane * 8]);

            #pragma unroll
            for (int mi = 0; mi < 4; ++mi)
                #pragma unroll
                for (int ni = 0; ni < 4; ++ni)
                    acc[mi][ni] = __builtin_amdgcn_mfma_f32_16x16x32_bf16(
                        af[mi], bfr[ni], acc[mi][ni], 0, 0, 0);

            __syncthreads();   // guards buf reuse; prefetch had compute-time to fly
        }

        // ---- epilogue: exp, diag mask, pos extraction, row+col sums ----
        // C/D layout (16x16): col = lane&15, row = q*4 + r
        float rsum[4][4];
        float csum[4] = {0.f, 0.f, 0.f, 0.f};
        #pragma unroll
        for (int mi = 0; mi < 4; ++mi)
            #pragma unroll
            for (int r = 0; r < 4; ++r) rsum[mi][r] = 0.0f;

        #pragma unroll
        for (int mi = 0; mi < 4; ++mi)
            #pragma unroll
            for (int ni = 0; ni < 4; ++ni)
                #pragma unroll
                for (int r = 0; r < 4; ++r) {
                    const int lr = wm + mi * 16 + q * 4 + r;
                    const int lc = wn + ni * 16 + l15;
                    float e = exp2f(acc[mi][ni][r] * TEN_LOG2E);
                    if (diag && lr == lc) e = 0.0f;      // mask self-similarity
                    rsum[mi][r] += e;
                    csum[ni]    += e;
                    if (ptile && lr == lc)
                        blk_pos += acc[mi][ni][r];       // cos of a positive pair
                }

        #pragma unroll
        for (int mi = 0; mi < 4; ++mi)
            #pragma unroll
            for (int r = 0; r < 4; ++r) {
                float v = rsum[mi][r];
                v += __shfl_xor(v, 1, 64);
                v += __shfl_xor(v, 2, 64);
                v += __shfl_xor(v, 4, 64);
                v += __shfl_xor(v, 8, 64);
                rsum[mi][r] = v;
            }
        if (l15 == 0) {
            #pragma unroll
            for (int mi = 0; mi < 4; ++mi)
                #pragma unroll
                for (int r = 0; r < 4; ++r)
                    atomicAdd(&row_s[ti * 128 + wm + mi * 16 + q * 4 + r], rsum[mi][r]);
        }
        if (!diag) {   // symmetric contribution to column rows
            #pragma unroll
            for (int ni = 0; ni < 4; ++ni) {
                float v = csum[ni];
                v += __shfl_xor(v, 16, 64);
                v += __shfl_xor(v, 32, 64);
                if (q == 0)
                    atomicAdd(&row_s[tj * 128 + wn + ni * 16 + l15], v);
            }
        }
    }

    // positive-pair contribution: pos_i = 10*cos, rows r and r+4096 share it -> x2
    if (hadP) {
        #pragma unroll
        for (int off = 32; off > 0; off >>= 1) blk_pos += __shfl_xor(blk_pos, off, 64);
        if (lane == 0)
            atomicAdd(out, blk_pos * (-20.0f / 8192.0f));
    }

    // ---- last block finalizes: sum log(row_s) ----
    __shared__ int lastflag;
    __shared__ float red[4];
    __syncthreads();
    if (tid == 0) {
        __threadfence();
        const int old = __hip_atomic_fetch_add(done, 1, __ATOMIC_ACQ_REL,
                                               __HIP_MEMORY_SCOPE_AGENT);
        lastflag = (old == NBLK - 1);
    }
    __syncthreads();
    if (!lastflag) return;

    float local = 0.0f;
    for (int i = tid; i < 8192; i += 256) {
        const float s = __hip_atomic_load(&row_s[i], __ATOMIC_RELAXED,
                                          __HIP_MEMORY_SCOPE_AGENT);
        local += __logf(s);
    }
    #pragma unroll
    for (int off = 32; off > 0; off >>= 1) local += __shfl_xor(local, off, 64);
    if ((tid & 63) == 0) red[tid >> 6] = local;
    __syncthreads();
    if (tid == 0)
        atomicAdd(out, (red[0] + red[1] + red[2] + red[3]) * (1.0f / 8192.0f));
}

// ---------------- Launch ----------------
extern "C" void kernel_launch(void* const* d_in, const int* in_sizes, int n_in,
                              void* d_out, int out_size, void* d_ws, size_t ws_size,
                              hipStream_t stream)
{
    const float* zi = (const float*)d_in[0];
    const float* zj = (const float*)d_in[1];

    ushort* packed = (ushort*)d_ws;                                    // 4 MB fragment-order bf16
    float* row_s   = (float*)((char*)d_ws + (4u << 20));               // 8192 fp32
    int*   done    = (int*)((char*)d_ws + (4u << 20) + (32u << 10));   // counter
    float* out     = (float*)d_out;

    hipLaunchKernelGGL(normalize_pack_kernel, dim3(512), dim3(256), 0, stream,
                       zi, zj, packed, row_s, done, out);
    hipLaunchKernelGGL(simexp_kernel, dim3(NBLK), dim3(256), 0, stream,
                       packed, row_s, done, out);
}

// Round 10
// 118.798 us; speedup vs baseline: 1.2516x; 1.2516x over previous
//
#include <hip/hip_runtime.h>
#include <hip/hip_bf16.h>
#include <stdint.h>

typedef short s16x8 __attribute__((ext_vector_type(8)));
typedef float f32x4 __attribute__((ext_vector_type(4)));

static constexpr int DDIM = 256;
static constexpr float TEN_LOG2E = 14.4269504088896340736f; // 10 * log2(e)

// ---------------- Kernel 1: normalize + pack into MFMA-fragment order ----------------
// 512 blocks x 256 threads; block g handles rows [16g, 16g+16). packed layout:
// packed[((g*8 + kt)*64 + lane)*8 .. +8] = bf16 P[16g + (lane&15)][kt*32 + (lane>>4)*8 ..]
// Each (group, kt) fragment is a contiguous 1KB block in exact lane order.
// Also zero-inits row_s[8192] (blocks 0..7) and out[0] (block 0).
__global__ __launch_bounds__(256) void normalize_pack_kernel(
    const float* __restrict__ zi, const float* __restrict__ zj,
    ushort* __restrict__ packed, float* __restrict__ row_s, float* __restrict__ out)
{
    __shared__ ushort lds[16 * 256];

    if (blockIdx.x < 8) {
        ((float4*)row_s)[blockIdx.x * 256 + threadIdx.x] = (float4){0.f, 0.f, 0.f, 0.f};
        if (blockIdx.x == 0 && threadIdx.x == 0) out[0] = 0.0f;
    }

    const int t = threadIdx.x;
    const int r = t >> 4;            // 0..15: row within group
    const int c = t & 15;            // 16 threads per row
    const int row = blockIdx.x * 16 + r;
    const float* src = (row < 4096) ? (zi + (size_t)row * DDIM)
                                    : (zj + (size_t)(row - 4096) * DDIM);
    float4 v[4];
    #pragma unroll
    for (int j = 0; j < 4; ++j) v[j] = ((const float4*)src)[c + j * 16];

    float ss = 0.0f;
    #pragma unroll
    for (int j = 0; j < 4; ++j)
        ss += v[j].x * v[j].x + v[j].y * v[j].y + v[j].z * v[j].z + v[j].w * v[j].w;
    ss += __shfl_xor(ss, 1, 64);
    ss += __shfl_xor(ss, 2, 64);
    ss += __shfl_xor(ss, 4, 64);
    ss += __shfl_xor(ss, 8, 64);
    const float inv = 1.0f / fmaxf(sqrtf(ss), 1e-8f);

    #pragma unroll
    for (int j = 0; j < 4; ++j) {
        ushort4 o;
        o.x = __builtin_bit_cast(unsigned short, __float2bfloat16(v[j].x * inv));
        o.y = __builtin_bit_cast(unsigned short, __float2bfloat16(v[j].y * inv));
        o.z = __builtin_bit_cast(unsigned short, __float2bfloat16(v[j].z * inv));
        o.w = __builtin_bit_cast(unsigned short, __float2bfloat16(v[j].w * inv));
        *(ushort4*)(lds + r * 256 + (c + j * 16) * 4) = o;
    }
    __syncthreads();

    #pragma unroll
    for (int h = 0; h < 2; ++h) {
        const int idx  = h * 256 + t;
        const int kt   = idx >> 6;
        const int lane = idx & 63;
        const int q    = lane >> 4;
        const int l15  = lane & 15;
        s16x8 frag = *(const s16x8*)(lds + l15 * 256 + kt * 32 + q * 8);
        ((s16x8*)packed)[(size_t)(blockIdx.x * 8 + kt) * 64 + lane] = frag;
    }
}

// ---------------- Kernel 2: upper-triangle Gram tiles, convoy-staggered K-loop -------
// 2080 blocks = 64*65/2 tiles of 128x128; 4 waves x (64x64 via 16x16x32 MFMA, 4x4
// frags). No LDS, no barriers: fragments are contiguous 1KB coalesced loads from the
// packed (fragment-order) array, L2-resident. NEW vs R6: each block starts its K-loop
// at kt0 = blockIdx&7 and wraps mod 8 (K-sum is commutative). Co-resident waves from
// different blocks then hit their load-latency windows at different phases instead of
// in lockstep convoys; intra-block A-sharing (waves 0/1 and 2/3) is preserved because
// the offset is block-uniform.
__global__ __launch_bounds__(256) void simexp_kernel(
    const ushort* __restrict__ packed,
    float* __restrict__ row_s,
    float* __restrict__ pos_out)
{
    const int tid  = threadIdx.x;
    const int w    = tid >> 6;
    const int lane = tid & 63;
    const int q    = lane >> 4;      // 0..3: K-octet of the MFMA operand
    const int l15  = lane & 15;
    const int wm   = (w >> 1) * 64;  // wave row offset in 128x128 tile
    const int wn   = (w & 1) * 64;   // wave col offset

    // ---- upper-triangle decode: block b -> (ti, tj), ti <= tj ----
    const int b = blockIdx.x;
    int ti = (int)(64.5f - sqrtf(64.5f * 64.5f - 2.0f * (float)b));
    while ((ti + 1) * 64 - ((ti + 1) * ti) / 2 <= b) ++ti;
    while (ti * 64 - (ti * (ti - 1)) / 2 > b) --ti;
    const int tj = ti + (b - (ti * 64 - (ti * (ti - 1)) / 2));
    const int r0 = ti * 128, c0 = tj * 128;
    const bool diag  = (ti == tj);
    const bool ptile = (tj == ti + 32);  // contains positive-pair diagonal

    // fragment base pointers into packed: group stride 4096 ushorts (8 kt x 1KB),
    // kt stride 512 ushorts (1KB)
    const int gA = (r0 + wm) >> 4;
    const int gB = (c0 + wn) >> 4;
    const ushort* pa[4];
    const ushort* pb[4];
    #pragma unroll
    for (int mi = 0; mi < 4; ++mi)
        pa[mi] = packed + (size_t)(gA + mi) * 4096 + (size_t)lane * 8;
    #pragma unroll
    for (int ni = 0; ni < 4; ++ni)
        pb[ni] = packed + (size_t)(gB + ni) * 4096 + (size_t)lane * 8;

    f32x4 acc[4][4];
    #pragma unroll
    for (int mi = 0; mi < 4; ++mi)
        #pragma unroll
        for (int ni = 0; ni < 4; ++ni)
            acc[mi][ni] = (f32x4){0.f, 0.f, 0.f, 0.f};

    const int kt0 = b & 7;   // convoy-desync phase offset (block-uniform)
    #pragma unroll
    for (int k = 0; k < 8; ++k) {
        const int kt = (k + kt0) & 7;
        s16x8 af[4], bfr[4];
        #pragma unroll
        for (int mi = 0; mi < 4; ++mi)
            af[mi] = *(const s16x8*)(pa[mi] + kt * 512);
        #pragma unroll
        for (int ni = 0; ni < 4; ++ni)
            bfr[ni] = *(const s16x8*)(pb[ni] + kt * 512);

        #pragma unroll
        for (int mi = 0; mi < 4; ++mi)
            #pragma unroll
            for (int ni = 0; ni < 4; ++ni)
                acc[mi][ni] = __builtin_amdgcn_mfma_f32_16x16x32_bf16(
                    af[mi], bfr[ni], acc[mi][ni], 0, 0, 0);
    }

    // ---- epilogue: exp, diag mask, positive extraction, row+col sums ----
    // C/D layout (16x16): col = lane&15, row = q*4 + r
    float rsum[4][4];
    float csum[4] = {0.f, 0.f, 0.f, 0.f};
    #pragma unroll
    for (int mi = 0; mi < 4; ++mi)
        #pragma unroll
        for (int r = 0; r < 4; ++r) rsum[mi][r] = 0.0f;

    #pragma unroll
    for (int mi = 0; mi < 4; ++mi)
        #pragma unroll
        for (int ni = 0; ni < 4; ++ni)
            #pragma unroll
            for (int r = 0; r < 4; ++r) {
                const int lr = wm + mi * 16 + q * 4 + r;
                const int lc = wn + ni * 16 + l15;
                float e = exp2f(acc[mi][ni][r] * TEN_LOG2E);
                if (diag && lr == lc) e = 0.0f;          // mask self-similarity
                rsum[mi][r] += e;
                csum[ni]    += e;
                if (ptile && lr == lc) {                 // positive pair: col = row + 4096
                    const float v = acc[mi][ni][r] * 10.0f;
                    pos_out[r0 + lr] = v;
                    pos_out[c0 + lr] = v;
                }
            }

    // row sums: reduce across the 16 lanes (cols) of each quad
    #pragma unroll
    for (int mi = 0; mi < 4; ++mi)
        #pragma unroll
        for (int r = 0; r < 4; ++r) {
            float v = rsum[mi][r];
            v += __shfl_xor(v, 1, 64);
            v += __shfl_xor(v, 2, 64);
            v += __shfl_xor(v, 4, 64);
            v += __shfl_xor(v, 8, 64);
            rsum[mi][r] = v;
        }
    if (l15 == 0) {
        #pragma unroll
        for (int mi = 0; mi < 4; ++mi)
            #pragma unroll
            for (int r = 0; r < 4; ++r)
                atomicAdd(&row_s[r0 + wm + mi * 16 + q * 4 + r], rsum[mi][r]);
    }

    // col sums (symmetric contribution): reduce across quads (rows), skip on diagonal
    if (!diag) {
        #pragma unroll
        for (int ni = 0; ni < 4; ++ni) {
            float v = csum[ni];
            v += __shfl_xor(v, 16, 64);
            v += __shfl_xor(v, 32, 64);
            if (q == 0)
                atomicAdd(&row_s[c0 + wn + ni * 16 + l15], v);
        }
    }
}

// ---------------- Kernel 3: finalize loss ----------------
__global__ __launch_bounds__(256) void finalize_kernel(
    const float* __restrict__ row_s, const float* __restrict__ pos,
    float* __restrict__ out)
{
    const int i = blockIdx.x * 256 + threadIdx.x;   // float4 index, 2048 total
    float4 s = ((const float4*)row_s)[i];
    float4 p = ((const float4*)pos)[i];
    float local = (__logf(s.x) - p.x) + (__logf(s.y) - p.y)
                + (__logf(s.z) - p.z) + (__logf(s.w) - p.w);
    #pragma unroll
    for (int off = 32; off > 0; off >>= 1) local += __shfl_xor(local, off, 64);
    __shared__ float red[4];
    if ((threadIdx.x & 63) == 0) red[threadIdx.x >> 6] = local;
    __syncthreads();
    if (threadIdx.x == 0)
        atomicAdd(out, (red[0] + red[1] + red[2] + red[3]) * (1.0f / 8192.0f));
}

// ---------------- Launch ----------------
extern "C" void kernel_launch(void* const* d_in, const int* in_sizes, int n_in,
                              void* d_out, int out_size, void* d_ws, size_t ws_size,
                              hipStream_t stream)
{
    const float* zi = (const float*)d_in[0];
    const float* zj = (const float*)d_in[1];

    ushort* packed = (ushort*)d_ws;                                    // 4 MB fragment-order bf16
    float* row_s   = (float*)((char*)d_ws + (4u << 20));               // 8192 fp32
    float* pos     = (float*)((char*)d_ws + (4u << 20) + (32u << 10)); // 8192 fp32
    float* out     = (float*)d_out;

    hipLaunchKernelGGL(normalize_pack_kernel, dim3(512), dim3(256), 0, stream,
                       zi, zj, packed, row_s, out);
    hipLaunchKernelGGL(simexp_kernel, dim3(2080), dim3(256), 0, stream,
                       packed, row_s, pos);
    hipLaunchKernelGGL(finalize_kernel, dim3(8), dim3(256), 0, stream, row_s, pos, out);
}

// Round 11
// 117.056 us; speedup vs baseline: 1.2702x; 1.0149x over previous
//
#include <hip/hip_runtime.h>
#include <hip/hip_bf16.h>
#include <stdint.h>

typedef float f32x4 __attribute__((ext_vector_type(4)));
typedef unsigned int uint32;

static constexpr int DDIM = 256;
static constexpr float TEN_LOG2E = 14.4269504088896340736f; // 10 * log2(e)

// ---------------- Kernel 1: normalize + quantize fp8 + pack into fragment-pair order --
// 512 blocks x 256 threads; block g handles rows [16g, 16g+16). packed layout (fp8):
// for kt-pair p in 0..3, 1KB block at byte offset ((g*4 + p)*64 + lane)*16 holding
//   bytes 0..7  = fp8 P[16g + (lane&15)][(2p)*32   + (lane>>4)*8 + j]   (frag kt=2p)
//   bytes 8..15 = fp8 P[16g + (lane&15)][(2p+1)*32 + (lane>>4)*8 + j]   (frag kt=2p+1)
// One 16B/lane coalesced load in kernel 2 yields TWO K=32 fragments.
// Also zero-inits row_s[8192] (blocks 0..7) and out[0] (block 0).
__global__ __launch_bounds__(256) void normalize_pack_kernel(
    const float* __restrict__ zi, const float* __restrict__ zj,
    unsigned char* __restrict__ packed, float* __restrict__ row_s,
    float* __restrict__ out)
{
    __shared__ unsigned char lds[16 * 256];

    if (blockIdx.x < 8) {
        ((float4*)row_s)[blockIdx.x * 256 + threadIdx.x] = (float4){0.f, 0.f, 0.f, 0.f};
        if (blockIdx.x == 0 && threadIdx.x == 0) out[0] = 0.0f;
    }

    const int t = threadIdx.x;
    const int r = t >> 4;            // 0..15: row within group
    const int c = t & 15;            // 16 threads per row
    const int row = blockIdx.x * 16 + r;
    const float* src = (row < 4096) ? (zi + (size_t)row * DDIM)
                                    : (zj + (size_t)(row - 4096) * DDIM);
    float4 v[4];
    #pragma unroll
    for (int j = 0; j < 4; ++j) v[j] = ((const float4*)src)[c + j * 16];

    float ss = 0.0f;
    #pragma unroll
    for (int j = 0; j < 4; ++j)
        ss += v[j].x * v[j].x + v[j].y * v[j].y + v[j].z * v[j].z + v[j].w * v[j].w;
    ss += __shfl_xor(ss, 1, 64);
    ss += __shfl_xor(ss, 2, 64);
    ss += __shfl_xor(ss, 4, 64);
    ss += __shfl_xor(ss, 8, 64);
    const float inv = 1.0f / fmaxf(sqrtf(ss), 1e-8f);

    // quantize to OCP e4m3 (HW cvt), 4 bytes per float4
    #pragma unroll
    for (int j = 0; j < 4; ++j) {
        uint32 pk = 0;
        pk = __builtin_amdgcn_cvt_pk_fp8_f32(v[j].x * inv, v[j].y * inv, pk, false);
        pk = __builtin_amdgcn_cvt_pk_fp8_f32(v[j].z * inv, v[j].w * inv, pk, true);
        *(uint32*)(lds + r * 256 + (c + j * 16) * 4) = pk;
    }
    __syncthreads();

    // repack: 4 kt-pairs x 64 lanes = 256 slots of 16B; one per thread
    const int p    = t >> 6;         // kt-pair 0..3
    const int lane = t & 63;
    const int q    = lane >> 4;
    const int l15  = lane & 15;
    uint2 lo = *(const uint2*)(lds + l15 * 256 + p * 64 + q * 8);        // frag kt=2p
    uint2 hi = *(const uint2*)(lds + l15 * 256 + p * 64 + 32 + q * 8);   // frag kt=2p+1
    uint4 o; o.x = lo.x; o.y = lo.y; o.z = hi.x; o.w = hi.y;
    ((uint4*)packed)[(size_t)(blockIdx.x * 4 + p) * 64 + lane] = o;
}

// ---------------- Kernel 2: upper-triangle Gram tiles, fp8 pair-fragments ------------
// 2080 blocks = 64*65/2 tiles of 128x128; 4 waves x (64x64 via 16x16x32 fp8 MFMA,
// 4x4 frags). No LDS, no barriers. Per kt-pair: 8 coalesced 1KB loads (each carrying
// TWO K=32 fragments) -> 32 MFMAs, i.e. 2x the MFMA-per-vmcnt-wait of the bf16
// version. packed is 2MB total -> fits each XCD L2 with headroom. XCD-contiguous
// tile remap (2080 = 8 x 260) keeps each XCD's A-panels L2-local.
__global__ __launch_bounds__(256) void simexp_kernel(
    const unsigned char* __restrict__ packed,
    float* __restrict__ row_s,
    float* __restrict__ pos_out)
{
    const int tid  = threadIdx.x;
    const int w    = tid >> 6;
    const int lane = tid & 63;
    const int q    = lane >> 4;      // 0..3: K-octet of the MFMA operand
    const int l15  = lane & 15;
    const int wm   = (w >> 1) * 64;  // wave row offset in 128x128 tile
    const int wn   = (w & 1) * 64;   // wave col offset

    // XCD-contiguous virtual tile id (blockIdx%8 ~ XCD on 8-XCD round-robin dispatch)
    const int b = (blockIdx.x & 7) * 260 + (blockIdx.x >> 3);

    // ---- upper-triangle decode: b -> (ti, tj), ti <= tj ----
    int ti = (int)(64.5f - sqrtf(64.5f * 64.5f - 2.0f * (float)b));
    while ((ti + 1) * 64 - ((ti + 1) * ti) / 2 <= b) ++ti;
    while (ti * 64 - (ti * (ti - 1)) / 2 > b) --ti;
    const int tj = ti + (b - (ti * 64 - (ti * (ti - 1)) / 2));
    const int r0 = ti * 128, c0 = tj * 128;
    const bool diag  = (ti == tj);
    const bool ptile = (tj == ti + 32);  // contains positive-pair diagonal

    // fragment-pair base pointers: group stride 4KB (4 pairs x 1KB), pair stride 1KB
    const int gA = (r0 + wm) >> 4;
    const int gB = (c0 + wn) >> 4;
    const unsigned char* pa[4];
    const unsigned char* pb[4];
    #pragma unroll
    for (int mi = 0; mi < 4; ++mi)
        pa[mi] = packed + (size_t)(gA + mi) * 4096 + (size_t)lane * 16;
    #pragma unroll
    for (int ni = 0; ni < 4; ++ni)
        pb[ni] = packed + (size_t)(gB + ni) * 4096 + (size_t)lane * 16;

    f32x4 acc[4][4];
    #pragma unroll
    for (int mi = 0; mi < 4; ++mi)
        #pragma unroll
        for (int ni = 0; ni < 4; ++ni)
            acc[mi][ni] = (f32x4){0.f, 0.f, 0.f, 0.f};

    #pragma unroll
    for (int p = 0; p < 4; ++p) {
        ulong2 af[4], bfr[4];
        #pragma unroll
        for (int mi = 0; mi < 4; ++mi)
            af[mi] = *(const ulong2*)(pa[mi] + p * 1024);
        #pragma unroll
        for (int ni = 0; ni < 4; ++ni)
            bfr[ni] = *(const ulong2*)(pb[ni] + p * 1024);

        #pragma unroll
        for (int mi = 0; mi < 4; ++mi)
            #pragma unroll
            for (int ni = 0; ni < 4; ++ni) {
                acc[mi][ni] = __builtin_amdgcn_mfma_f32_16x16x32_fp8_fp8(
                    (long)af[mi].x, (long)bfr[ni].x, acc[mi][ni], 0, 0, 0);
                acc[mi][ni] = __builtin_amdgcn_mfma_f32_16x16x32_fp8_fp8(
                    (long)af[mi].y, (long)bfr[ni].y, acc[mi][ni], 0, 0, 0);
            }
    }

    // ---- epilogue: exp, diag mask, positive extraction, row+col sums ----
    // C/D layout (16x16, dtype-independent): col = lane&15, row = q*4 + r
    float rsum[4][4];
    float csum[4] = {0.f, 0.f, 0.f, 0.f};
    #pragma unroll
    for (int mi = 0; mi < 4; ++mi)
        #pragma unroll
        for (int r = 0; r < 4; ++r) rsum[mi][r] = 0.0f;

    #pragma unroll
    for (int mi = 0; mi < 4; ++mi)
        #pragma unroll
        for (int ni = 0; ni < 4; ++ni)
            #pragma unroll
            for (int r = 0; r < 4; ++r) {
                const int lr = wm + mi * 16 + q * 4 + r;
                const int lc = wn + ni * 16 + l15;
                float e = exp2f(acc[mi][ni][r] * TEN_LOG2E);
                if (diag && lr == lc) e = 0.0f;          // mask self-similarity
                rsum[mi][r] += e;
                csum[ni]    += e;
                if (ptile && lr == lc) {                 // positive pair: col = row + 4096
                    const float v = acc[mi][ni][r] * 10.0f;
                    pos_out[r0 + lr] = v;
                    pos_out[c0 + lr] = v;
                }
            }

    // row sums: reduce across the 16 lanes (cols) of each quad
    #pragma unroll
    for (int mi = 0; mi < 4; ++mi)
        #pragma unroll
        for (int r = 0; r < 4; ++r) {
            float v = rsum[mi][r];
            v += __shfl_xor(v, 1, 64);
            v += __shfl_xor(v, 2, 64);
            v += __shfl_xor(v, 4, 64);
            v += __shfl_xor(v, 8, 64);
            rsum[mi][r] = v;
        }
    if (l15 == 0) {
        #pragma unroll
        for (int mi = 0; mi < 4; ++mi)
            #pragma unroll
            for (int r = 0; r < 4; ++r)
                atomicAdd(&row_s[r0 + wm + mi * 16 + q * 4 + r], rsum[mi][r]);
    }

    // col sums (symmetric contribution): reduce across quads (rows), skip on diagonal
    if (!diag) {
        #pragma unroll
        for (int ni = 0; ni < 4; ++ni) {
            float v = csum[ni];
            v += __shfl_xor(v, 16, 64);
            v += __shfl_xor(v, 32, 64);
            if (q == 0)
                atomicAdd(&row_s[c0 + wn + ni * 16 + l15], v);
        }
    }
}

// ---------------- Kernel 3: finalize loss ----------------
__global__ __launch_bounds__(256) void finalize_kernel(
    const float* __restrict__ row_s, const float* __restrict__ pos,
    float* __restrict__ out)
{
    const int i = blockIdx.x * 256 + threadIdx.x;   // float4 index, 2048 total
    float4 s = ((const float4*)row_s)[i];
    float4 p = ((const float4*)pos)[i];
    float local = (__logf(s.x) - p.x) + (__logf(s.y) - p.y)
                + (__logf(s.z) - p.z) + (__logf(s.w) - p.w);
    #pragma unroll
    for (int off = 32; off > 0; off >>= 1) local += __shfl_xor(local, off, 64);
    __shared__ float red[4];
    if ((threadIdx.x & 63) == 0) red[threadIdx.x >> 6] = local;
    __syncthreads();
    if (threadIdx.x == 0)
        atomicAdd(out, (red[0] + red[1] + red[2] + red[3]) * (1.0f / 8192.0f));
}

// ---------------- Launch ----------------
extern "C" void kernel_launch(void* const* d_in, const int* in_sizes, int n_in,
                              void* d_out, int out_size, void* d_ws, size_t ws_size,
                              hipStream_t stream)
{
    const float* zi = (const float*)d_in[0];
    const float* zj = (const float*)d_in[1];

    unsigned char* packed = (unsigned char*)d_ws;                      // 2 MB fp8 fragment pairs
    float* row_s   = (float*)((char*)d_ws + (4u << 20));               // 8192 fp32
    float* pos     = (float*)((char*)d_ws + (4u << 20) + (32u << 10)); // 8192 fp32
    float* out     = (float*)d_out;

    hipLaunchKernelGGL(normalize_pack_kernel, dim3(512), dim3(256), 0, stream,
                       zi, zj, packed, row_s, out);
    hipLaunchKernelGGL(simexp_kernel, dim3(2080), dim3(256), 0, stream,
                       packed, row_s, pos);
    hipLaunchKernelGGL(finalize_kernel, dim3(8), dim3(256), 0, stream, row_s, pos, out);
}